// Round 11
// baseline (423.711 us; speedup 1.0000x reference)
//
#include <hip/hip_runtime.h>
#include <hip/hip_bf16.h>

// Max-tree (component tree) per channel, 64x64x3. Outputs (float32):
// parents [3,4096] then altitudes [3,4096].
//
// ranks = stable descending sort position (distinct, 0 = highest f) act as
// altitudes; rank-image max-tree's uncompressed pixel-parent == reference's
// (validated r2-r10). Distinct ranks => UNIQUE tree => order-independent
// concurrent CAS-based ordered union over all 8064 edges (validated r5-r10).
//
// r11 = r10 + FAR-HINT SKIP LIST: st[x] = {parw, skipw, farw, rank} (16B).
//  - farw[x] = (rank(t)<<12)|t, t ANY known ancestor of x — same invariant
//    class as skipw, so all prior safety arguments apply unchanged.
//  - update: every 8 advances write farw[chk] = current position; at walk
//    end / successful CAS write farw[chk] = y (then a genuine ancestor).
//  - hop = usable hint (far|skip) with max rank <= ry; else parent logic.
//  - progress: hints point to strict ancestors (rank strictly ascends) =>
//    rank(x) strictly increases per hop; rank guard prevents overshoot;
//    rank==ry <=> node==y (distinct ranks).
//
// Safety recap (r5-r10, schedule-agnostic): parw CAS is ABA-safe (non-root
// parent-rank strictly decreases; self word never recurs); climb on stale
// parent safe (splices only INSERT between x and parent => once-read parent
// stays an ancestor); racy hint stores are word-atomic, any value written
// is a valid ancestor. Canon closed form validated r2-r10.

#define N_PIX 4096
#define CH 3
#define CHK_DIST 8

// ---------------------------------------------------------------------------
// K1: stable descending rank: rank(p) = #{f[q]>f[p]} + #{f[q]==f[p], q<p}
// ---------------------------------------------------------------------------
__global__ __launch_bounds__(256) void ct_rank(const float* __restrict__ vw,
                                               int* __restrict__ rank_g) {
    __shared__ __align__(16) float vals[N_PIX];
    const int c   = blockIdx.x >> 4;
    const int seg = blockIdx.x & 15;
    const int tid = threadIdx.x;
    for (int i = tid; i < N_PIX; i += 256) vals[i] = vw[i * CH + c];
    __syncthreads();

    const int   p  = (seg << 8) + tid;
    const float vp = vals[p];
    int cnt = 0;
    const float4* v4 = reinterpret_cast<const float4*>(vals);
#pragma unroll 4
    for (int j4 = 0; j4 < N_PIX / 4; ++j4) {
        float4 q = v4[j4];
        int j = j4 << 2;
        cnt += (q.x > vp) || ((q.x == vp) && (j     < p));
        cnt += (q.y > vp) || ((q.y == vp) && (j + 1 < p));
        cnt += (q.z > vp) || ((q.z == vp) && (j + 2 < p));
        cnt += (q.w > vp) || ((q.w == vp) && (j + 3 < p));
    }
    rank_g[(c << 12) + p] = cnt;
}

// ---------------------------------------------------------------------------
// K2: concurrent ordered union (scattered edges, far-hint skip list) + canon.
// One block per channel, 1024 threads, 8 edge slots per thread.
// ---------------------------------------------------------------------------
__global__ __launch_bounds__(1024) void ct_tree(const float* __restrict__ vw,
                                                const int* __restrict__ rank_g,
                                                float* __restrict__ out) {
    __shared__ __align__(16) unsigned st[N_PIX][4];  // 64 KB {par,skip,far,rank}
    __shared__ float vals[N_PIX];                    // 16 KB
    const int c   = blockIdx.x;
    const int tid = threadIdx.x;

    for (int p = tid; p < N_PIX; p += 1024) {
        const unsigned r  = (unsigned)rank_g[(c << 12) + p];
        const unsigned sw = (r << 12) | (unsigned)p;
        st[p][0] = sw; st[p][1] = sw; st[p][2] = sw; st[p][3] = r;
        vals[p]  = vw[p * CH + c];
    }
    __syncthreads();

    // ---- init 8 walk slots (scattered: e = k*1024 + tid) ----
    unsigned curwA[8], ywA[8];
    int pxA[8], chkA[8];          // chkA: node in bits 0-11, cnt in bits 16+
    unsigned act = 0;
#pragma unroll
    for (int k = 0; k < 8; ++k) {
        curwA[k] = 0; ywA[k] = 0; pxA[k] = -1; chkA[k] = 0;
        const int e = (k << 10) + tid;
        if (e < 8064) {
            int x, y;
            if (e < 4032) { const int row = e / 63; x = row * 64 + (e - row * 63); y = x + 1; }
            else          { const int e2 = e - 4032; x = ((e2 >> 6) << 6) + (e2 & 63); y = x + 64; }
            unsigned rx = st[x][3], ry = st[y][3];
            if (rx > ry) { int t = x; x = y; y = t; unsigned tr = rx; rx = ry; ry = tr; }
            curwA[k] = (rx << 12) | (unsigned)x;
            ywA[k]   = (ry << 12) | (unsigned)y;
            chkA[k]  = x;
            act     |= 1u << k;
        }
    }

    // ---- one macro-step for slot k on loaded state ----
    auto step = [&](int k, unsigned long long lv, unsigned fw) {
        const unsigned curw = curwA[k];
        const int      x    = (int)(curw & 0xFFFu);
        const unsigned yw   = ywA[k];
        const unsigned ry   = yw >> 12;
        const unsigned w    = (unsigned)lv;          // parw[x]
        const unsigned sk   = (unsigned)(lv >> 32);  // skipw[x]
        if (pxA[k] >= 0) { st[pxA[k]][1] = sk; pxA[k] = -1; }   // deferred halving

        // hop = usable hint with max rank <= ry
        unsigned best = 0; bool hashop = false;
        if ((fw & 0xFFFu) != (unsigned)x && (fw >> 12) <= ry) { best = fw; hashop = true; }
        if ((sk & 0xFFFu) != (unsigned)x && (sk >> 12) <= ry &&
            (!hashop || (sk >> 12) > (best >> 12)))           { best = sk; hashop = true; }

        if (hashop) {
            if ((best & 0xFFFu) == (yw & 0xFFFu)) {            // reached y: done
                st[chkA[k] & 0xFFF][2] = yw;                   // y ancestor of chk
                act &= ~(1u << k);
            } else {
                pxA[k]  = x;
                curwA[k] = best;
                int cc = chkA[k] + (1 << 16);
                if ((cc >> 16) >= CHK_DIST) { st[cc & 0xFFF][2] = best; cc = (int)(best & 0xFFFu); }
                chkA[k] = cc;
            }
            return;
        }

        const unsigned p  = w & 0xFFFu;
        const unsigned rp = w >> 12;
        if (p == (unsigned)x) {                                // root: attach y
            if (atomicCAS(&st[x][0], w, yw) == w) {
                st[x][1] = yw;
                st[chkA[k] & 0xFFF][2] = yw;
                act &= ~(1u << k);
            }
        } else if (rp < ry) {                                  // climb + memo
            st[x][1] = w;
            curwA[k] = w;
            int cc = chkA[k] + (1 << 16);
            if ((cc >> 16) >= CHK_DIST) { st[cc & 0xFFF][2] = w; cc = (int)(w & 0xFFFu); }
            chkA[k] = cc;
        } else if (rp > ry) {                                  // splice y below p
            if (atomicCAS(&st[x][0], w, yw) == w) {
                st[x][1] = yw;
                st[chkA[k] & 0xFFF][2] = yw;                   // y now ancestor of chk
                curwA[k] = yw;                                 // continue from y
                ywA[k]   = w;                                  // ...inserting p
                chkA[k]  = (int)(yw & 0xFFFu);                 // reset chk at y
            }
        } else {                                               // rp==ry => p==y
            st[chkA[k] & 0xFFF][2] = yw;
            act &= ~(1u << k);
        }
    };

    // ---- interleaved macro-step loop: gated batched loads, then steps ----
    while (act) {
        unsigned long long ld[8];
        unsigned           lf[8];
#pragma unroll
        for (int k = 0; k < 8; ++k)
            if (act & (1u << k)) {
                const int x = (int)(curwA[k] & 0xFFFu);
                ld[k] = *((volatile unsigned long long*)&st[x][0]);
                lf[k] = *((volatile unsigned*)&st[x][2]);
            }
#pragma unroll
        for (int k = 0; k < 8; ++k)
            if (act & (1u << k)) step(k, ld[k], lf[k]);
    }
    __syncthreads();

    // ---- canon (g[p] = climb-from-parent-while-f-equal) + output ----
    for (int p = tid; p < N_PIX; p += 1024) {
        int q = st[p][0] & 0xFFF;
        const float fq = vals[q];
        for (;;) {
            const int qp = st[q][0] & 0xFFF;
            if (qp == q) break;
            if (vals[qp] != fq) break;
            q = qp;
        }
        out[(c << 12) + p] = (float)q;
        out[CH * N_PIX + (c << 12) + p] = vals[p];
    }
}

extern "C" void kernel_launch(void* const* d_in, const int* in_sizes, int n_in,
                              void* d_out, int out_size, void* d_ws, size_t ws_size,
                              hipStream_t stream) {
    const float* vw = (const float*)d_in[0];
    float* out = (float*)d_out;

    int* rank_g = (int*)d_ws;   // 3*4096 ints

    ct_rank<<<48, 256, 0, stream>>>(vw, rank_g);
    ct_tree<<<CH, 1024, 0, stream>>>(vw, rank_g, out);
}

// Round 12
// 366.338 us; speedup vs baseline: 1.1566x; 1.1566x over previous
//
#include <hip/hip_runtime.h>
#include <hip/hip_bf16.h>

// Max-tree (component tree) per channel, 64x64x3. Outputs (float32):
// parents [3,4096] then altitudes [3,4096].
//
// ranks = stable descending sort position (distinct, 0 = highest f) act as
// altitudes; rank-image max-tree's uncompressed pixel-parent == reference's
// (validated r2-r11). Distinct ranks => UNIQUE tree => order-independent
// concurrent CAS-based ordered union over all 8064 edges (validated r5-r11).
//
// r12 = r10 (scattered edges, fused b64 par/skip state at stride 8B —
// NEVER 16B stride: r11's [N][4] layout hit 8 banks only, 3x conflicts)
// + two hint-policy fixes:
//  (1) climb stores skipw[x]=parent ONLY if current hint is self — on the
//      climb path a non-self hint has rank > ry > rank(parent), i.e. it is
//      strictly deeper; r10 was vandalizing matured trunk hints.
//  (2) end-of-walk entry compression: walk tracks entry node x0; on every
//      terminal event and successful splice, skipw[x0] = yw (y is attached
//      at that moment and an ancestor of x0: all moves from x0 were
//      ancestor-moves and y sits above the reached node). Splice resets
//      x0 = y. One extra store per walk; entry points of trunk
//      re-traversals jump straight to the insertion depth.
//
// Safety (r5-r11, schedule-agnostic): parw CAS is ABA-safe (non-root
// parent-rank strictly decreases; self word never recurs); climb on stale
// parent safe (splices only INSERT between x and parent => once-read parent
// stays an ancestor); skipw[n]=(rank(t)<<12)|t with t ancestor-or-self,
// jump guarded by rank(t)<=ry (ranks strictly ascend along root paths;
// distinct ranks => rank==ry <=> node==y); racy 32-bit stores word-atomic,
// any written value is a valid ancestor.
// Canon closed form g[p] = climb-from-parent-while-f-equal (validated r2-r11).

#define N_PIX 4096
#define CH 3

// ---------------------------------------------------------------------------
// K1: stable descending rank: rank(p) = #{f[q]>f[p]} + #{f[q]==f[p], q<p}
// ---------------------------------------------------------------------------
__global__ __launch_bounds__(256) void ct_rank(const float* __restrict__ vw,
                                               int* __restrict__ rank_g) {
    __shared__ __align__(16) float vals[N_PIX];
    const int c   = blockIdx.x >> 4;
    const int seg = blockIdx.x & 15;
    const int tid = threadIdx.x;
    for (int i = tid; i < N_PIX; i += 256) vals[i] = vw[i * CH + c];
    __syncthreads();

    const int   p  = (seg << 8) + tid;
    const float vp = vals[p];
    int cnt = 0;
    const float4* v4 = reinterpret_cast<const float4*>(vals);
#pragma unroll 4
    for (int j4 = 0; j4 < N_PIX / 4; ++j4) {
        float4 q = v4[j4];
        int j = j4 << 2;
        cnt += (q.x > vp) || ((q.x == vp) && (j     < p));
        cnt += (q.y > vp) || ((q.y == vp) && (j + 1 < p));
        cnt += (q.z > vp) || ((q.z == vp) && (j + 2 < p));
        cnt += (q.w > vp) || ((q.w == vp) && (j + 3 < p));
    }
    rank_g[(c << 12) + p] = cnt;
}

// ---------------------------------------------------------------------------
// K2: concurrent ordered union (scattered edges, gated b64 loads, entry
// compression) + canon. One block/channel, 1024 threads, 8 slots/thread.
// ---------------------------------------------------------------------------
__global__ __launch_bounds__(1024) void ct_tree(const float* __restrict__ vw,
                                                const int* __restrict__ rank_g,
                                                float* __restrict__ out) {
    __shared__ __align__(16) unsigned state[2 * N_PIX];  // 32 KB (parw,skipw)
    __shared__ unsigned short rank16[N_PIX];             // 8 KB
    __shared__ float          vals[N_PIX];               // 16 KB
    const int c   = blockIdx.x;
    const int tid = threadIdx.x;

    for (int p = tid; p < N_PIX; p += 1024) {
        const unsigned r = (unsigned)rank_g[(c << 12) + p];
        rank16[p]        = (unsigned short)r;
        state[2 * p]     = (r << 12) | (unsigned)p;      // parw (self = root)
        state[2 * p + 1] = (r << 12) | (unsigned)p;      // skipw (self hint)
        vals[p]          = vw[p * CH + c];
    }
    __syncthreads();

    // ---- init 8 walk slots (scattered: e = k*1024 + tid) ----
    int xA[8], pxA[8], x0A[8];
    unsigned ywA[8];
    unsigned act = 0;
#pragma unroll
    for (int k = 0; k < 8; ++k) {
        xA[k] = 0; pxA[k] = -1; x0A[k] = 0; ywA[k] = 0;
        const int e = (k << 10) + tid;
        if (e < 8064) {
            int x, y;
            if (e < 4032) { const int row = e / 63; x = row * 64 + (e - row * 63); y = x + 1; }
            else          { const int e2 = e - 4032; x = ((e2 >> 6) << 6) + (e2 & 63); y = x + 64; }
            unsigned rx = rank16[x], ry = rank16[y];
            if (rx > ry) { int t = x; x = y; y = t; unsigned tr = rx; rx = ry; ry = tr; }
            xA[k]  = x;
            x0A[k] = x;
            ywA[k] = (ry << 12) | (unsigned)y;
            act   |= 1u << k;
        }
    }

    // ---- one macro-step for slot k on loaded 64-bit state ----
    auto step = [&](int k, unsigned long long lv) {
        const int      x  = xA[k];
        const unsigned yw = ywA[k];
        const unsigned ry = yw >> 12;
        const unsigned w  = (unsigned)lv;          // parw[x]
        const unsigned sk = (unsigned)(lv >> 32);  // skipw[x]
        if (pxA[k] >= 0) { state[2 * pxA[k] + 1] = sk; pxA[k] = -1; }  // halving
        const unsigned s = sk & 0xFFFu;
        if (s != (unsigned)x && (sk >> 12) <= ry) {            // jump via hint
            if (s == (yw & 0xFFFu)) {                          // reached y: done
                state[2 * x0A[k] + 1] = yw;                    // entry compression
                act &= ~(1u << k);
            }
            else { pxA[k] = x; xA[k] = (int)s; }
            return;
        }
        const unsigned p  = w & 0xFFFu;
        const unsigned rp = w >> 12;
        if (p == (unsigned)x) {                                // root: attach y
            if (atomicCAS(&state[2 * x], w, yw) == w) {
                state[2 * x + 1] = yw;
                state[2 * x0A[k] + 1] = yw;                    // entry compression
                act &= ~(1u << k);
            }
        } else if (rp < ry) {                                  // climb
            if (s == (unsigned)x) state[2 * x + 1] = w;        // memo only if no hint
            xA[k] = (int)p;
        } else if (rp > ry) {                                  // splice y below p
            if (atomicCAS(&state[2 * x], w, yw) == w) {
                state[2 * x + 1] = yw;
                state[2 * x0A[k] + 1] = yw;                    // entry compression
                xA[k]  = (int)(yw & 0xFFFu);                   // continue from y
                x0A[k] = xA[k];                                // new entry = y
                ywA[k] = w;                                    // ...inserting p
            }
        } else {                                               // rp==ry => p==y
            state[2 * x0A[k] + 1] = yw;                        // entry compression
            act &= ~(1u << k);
        }
    };

    // ---- interleaved macro-step loop: gated batched loads, then steps ----
    while (act) {
        unsigned long long ld[8];
#pragma unroll
        for (int k = 0; k < 8; ++k)
            if (act & (1u << k))
                ld[k] = *((volatile unsigned long long*)&state[2 * xA[k]]);
#pragma unroll
        for (int k = 0; k < 8; ++k)
            if (act & (1u << k)) step(k, ld[k]);
    }
    __syncthreads();

    // ---- canon (g[p] = climb-from-parent-while-f-equal) + output ----
    for (int p = tid; p < N_PIX; p += 1024) {
        int q = state[2 * p] & 0xFFF;
        const float fq = vals[q];
        for (;;) {
            const int qp = state[2 * q] & 0xFFF;
            if (qp == q) break;
            if (vals[qp] != fq) break;
            q = qp;
        }
        out[(c << 12) + p] = (float)q;
        out[CH * N_PIX + (c << 12) + p] = vals[p];
    }
}

extern "C" void kernel_launch(void* const* d_in, const int* in_sizes, int n_in,
                              void* d_out, int out_size, void* d_ws, size_t ws_size,
                              hipStream_t stream) {
    const float* vw = (const float*)d_in[0];
    float* out = (float*)d_out;

    int* rank_g = (int*)d_ws;   // 3*4096 ints

    ct_rank<<<48, 256, 0, stream>>>(vw, rank_g);
    ct_tree<<<CH, 1024, 0, stream>>>(vw, rank_g, out);
}

// Round 13
// 292.857 us; speedup vs baseline: 1.4468x; 1.2509x over previous
//
#include <hip/hip_runtime.h>
#include <hip/hip_bf16.h>

// Max-tree (component tree) per channel, 64x64x3. Outputs (float32):
// parents [3,4096] then altitudes [3,4096].
//
// ranks = stable descending sort position (distinct, 0 = highest f) act as
// altitudes; rank-image max-tree's uncompressed pixel-parent == reference's
// (validated r2-r12). Distinct ranks => UNIQUE tree => order-independent
// incremental edge insertion via concurrent CAS splice-walks (r5-r12).
//
// r13 structure (walk-length bounding + CU utilization):
//  K1: 48 blocks = (channel, strip of 4 rows). Computes global ranks (as
//      before) AND inserts the strip's 444 intra-strip edges concurrently
//      in a 256-node LDS state -> walks bounded by strip depth, 48 CUs hot.
//  K2: 3 blocks. Loads the 16 strip forests, inserts the 960 cross-strip
//      edges (1 walk/thread, boundaries scattered across lanes), canon,
//      output. Insertion order freedom makes this exactly equivalent
//      (same unique tree).
//
// Safety (r5-r12, schedule/subset-agnostic): parw CAS is ABA-safe (non-root
// parent-rank strictly decreases; self word never recurs); climb on stale
// parent safe (splices only INSERT between x and parent); skipw hints are
// ancestors-or-self, jump guarded by rank<=ry (ranks strictly ascend along
// root paths; distinct ranks => rank==ry <=> node==y); racy 32-bit hint
// stores word-atomic. State stride 8B (16 banks) — never 16B (r11 lesson).
// Canon closed form g[p] = climb-from-parent-while-f-equal (validated r2-r12).

#define N_PIX 4096
#define CH 3

// ---------------------------------------------------------------------------
// K1: rank + intra-strip concurrent build. 48 blocks x 256 threads.
// ---------------------------------------------------------------------------
__global__ __launch_bounds__(256) void ct_rank_build(const float* __restrict__ vw,
                                                     int* __restrict__ rank_g,
                                                     unsigned* __restrict__ word_g) {
    __shared__ __align__(16) float vals[N_PIX];          // 16 KB
    __shared__ unsigned short rankS[256];
    __shared__ __align__(8) unsigned st[2 * 256];        // 2 KB (parw,skipw)
    const int c    = blockIdx.x >> 4;
    const int seg  = blockIdx.x & 15;
    const int tid  = threadIdx.x;
    const int base = seg << 8;

    for (int i = tid; i < N_PIX; i += 256) vals[i] = vw[i * CH + c];
    __syncthreads();

    // ---- global stable descending rank of this thread's pixel ----
    const int   p  = base + tid;
    const float vp = vals[p];
    int cnt = 0;
    const float4* v4 = reinterpret_cast<const float4*>(vals);
#pragma unroll 4
    for (int j4 = 0; j4 < N_PIX / 4; ++j4) {
        float4 q = v4[j4];
        int j = j4 << 2;
        cnt += (q.x > vp) || ((q.x == vp) && (j     < p));
        cnt += (q.y > vp) || ((q.y == vp) && (j + 1 < p));
        cnt += (q.z > vp) || ((q.z == vp) && (j + 2 < p));
        cnt += (q.w > vp) || ((q.w == vp) && (j + 3 < p));
    }
    rank_g[(c << 12) + p] = cnt;
    rankS[tid] = (unsigned short)cnt;
    const unsigned selfw = ((unsigned)cnt << 12) | (unsigned)p;  // global id
    st[2 * tid]     = selfw;                                     // parw (root)
    st[2 * tid + 1] = selfw;                                     // skipw (self)
    __syncthreads();

    // ---- insert 444 intra-strip edges (2 slots/thread), local indexing ----
    int xlA[2], pxA[2], x0A[2];
    unsigned ywA[2];
    unsigned act = 0;
#pragma unroll
    for (int k = 0; k < 2; ++k) {
        xlA[k] = 0; pxA[k] = -1; x0A[k] = 0; ywA[k] = 0;
        const int e = (k << 8) + tid;
        if (e < 444) {
            int xl, yl;
            if (e < 252) { const int lr = e / 63; xl = (lr << 6) + (e - lr * 63); yl = xl + 1; }
            else         { const int e2 = e - 252; xl = ((e2 >> 6) << 6) + (e2 & 63); yl = xl + 64; }
            unsigned rx = rankS[xl], ry = rankS[yl];
            if (rx > ry) { int t = xl; xl = yl; yl = t; unsigned tr = rx; rx = ry; ry = tr; }
            xlA[k]  = xl;
            x0A[k]  = xl;
            ywA[k]  = (ry << 12) | (unsigned)(base + yl);
            act    |= 1u << k;
        }
    }

    auto stepL = [&](int k, unsigned long long lv) {
        const int      xl = xlA[k];
        const unsigned xg = (unsigned)(base + xl);
        const unsigned yw = ywA[k];
        const unsigned ry = yw >> 12;
        const unsigned w  = (unsigned)lv;
        const unsigned sk = (unsigned)(lv >> 32);
        if (pxA[k] >= 0) { st[2 * pxA[k] + 1] = sk; pxA[k] = -1; }
        const unsigned s = sk & 0xFFFu;
        if (s != xg && (sk >> 12) <= ry) {                     // hint jump
            if (s == (yw & 0xFFFu)) { st[2 * x0A[k] + 1] = yw; act &= ~(1u << k); }
            else { pxA[k] = xl; xlA[k] = (int)(s & 255u); }
            return;
        }
        const unsigned pg = w & 0xFFFu, rp = w >> 12;
        if (pg == xg) {                                        // root: attach y
            if (atomicCAS(&st[2 * xl], w, yw) == w) {
                st[2 * xl + 1] = yw; st[2 * x0A[k] + 1] = yw;
                act &= ~(1u << k);
            }
        } else if (rp < ry) {                                  // climb
            if (s == xg) st[2 * xl + 1] = w;
            xlA[k] = (int)(pg & 255u);
        } else if (rp > ry) {                                  // splice
            if (atomicCAS(&st[2 * xl], w, yw) == w) {
                st[2 * xl + 1] = yw; st[2 * x0A[k] + 1] = yw;
                xlA[k] = (int)(yw & 255u); x0A[k] = xlA[k]; ywA[k] = w;
            }
        } else { st[2 * x0A[k] + 1] = yw; act &= ~(1u << k); } // p==y
    };

    while (act) {
        unsigned long long ld[2];
#pragma unroll
        for (int k = 0; k < 2; ++k)
            if (act & (1u << k))
                ld[k] = *((volatile unsigned long long*)&st[2 * xlA[k]]);
#pragma unroll
        for (int k = 0; k < 2; ++k)
            if (act & (1u << k)) stepL(k, ld[k]);
    }
    __syncthreads();

    word_g[2 * ((c << 12) + p)]     = st[2 * tid];
    word_g[2 * ((c << 12) + p) + 1] = st[2 * tid + 1];
}

// ---------------------------------------------------------------------------
// K2: assemble strips via 960 cross edges + canon + output. 3 blocks.
// ---------------------------------------------------------------------------
__global__ __launch_bounds__(1024) void ct_assemble(const float* __restrict__ vw,
                                                    const int* __restrict__ rank_g,
                                                    const unsigned* __restrict__ word_g,
                                                    float* __restrict__ out) {
    __shared__ __align__(16) unsigned state[2 * N_PIX];  // 32 KB
    __shared__ float vals[N_PIX];                        // 16 KB
    const int c   = blockIdx.x;
    const int tid = threadIdx.x;

    for (int p = tid; p < N_PIX; p += 1024) {
        state[2 * p]     = word_g[2 * ((c << 12) + p)];
        state[2 * p + 1] = word_g[2 * ((c << 12) + p) + 1];
        vals[p]          = vw[p * CH + c];
    }
    __syncthreads();

    // ---- one cross edge per thread (tid < 960), boundaries scattered ----
    int x = 0, px = -1, x0 = 0;
    unsigned yw = 0;
    bool on = false;
    if (tid < 960) {
        const int b   = tid % 15;
        const int col = tid / 15;
        int xg = ((((b << 2) + 3)) << 6) + col;   // row 4b+3
        int yg = xg + 64;                         // row 4b+4
        unsigned rx = (unsigned)rank_g[(c << 12) + xg];
        unsigned ry = (unsigned)rank_g[(c << 12) + yg];
        if (rx > ry) { int t = xg; xg = yg; yg = t; unsigned tr = rx; rx = ry; ry = tr; }
        x = xg; x0 = xg; yw = (ry << 12) | (unsigned)yg;
        on = true;
    }

    while (on) {
        const unsigned long long lv = *((volatile unsigned long long*)&state[2 * x]);
        const unsigned w  = (unsigned)lv;
        const unsigned sk = (unsigned)(lv >> 32);
        const unsigned ry = yw >> 12;
        if (px >= 0) { state[2 * px + 1] = sk; px = -1; }
        const unsigned s = sk & 0xFFFu;
        if (s != (unsigned)x && (sk >> 12) <= ry) {            // hint jump
            if (s == (yw & 0xFFFu)) { state[2 * x0 + 1] = yw; on = false; }
            else { px = x; x = (int)s; }
            continue;
        }
        const unsigned p = w & 0xFFFu, rp = w >> 12;
        if (p == (unsigned)x) {                                // root: attach y
            if (atomicCAS(&state[2 * x], w, yw) == w) {
                state[2 * x + 1] = yw; state[2 * x0 + 1] = yw;
                on = false;
            }
        } else if (rp < ry) {                                  // climb
            if (s == (unsigned)x) state[2 * x + 1] = w;
            x = (int)p;
        } else if (rp > ry) {                                  // splice
            if (atomicCAS(&state[2 * x], w, yw) == w) {
                state[2 * x + 1] = yw; state[2 * x0 + 1] = yw;
                x = (int)(yw & 0xFFFu); x0 = x; yw = w;
            }
        } else { state[2 * x0 + 1] = yw; on = false; }         // p==y
    }
    __syncthreads();

    // ---- canon (g[p] = climb-from-parent-while-f-equal) + output ----
    for (int p = tid; p < N_PIX; p += 1024) {
        int q = state[2 * p] & 0xFFF;
        const float fq = vals[q];
        for (;;) {
            const int qp = state[2 * q] & 0xFFF;
            if (qp == q) break;
            if (vals[qp] != fq) break;
            q = qp;
        }
        out[(c << 12) + p] = (float)q;
        out[CH * N_PIX + (c << 12) + p] = vals[p];
    }
}

extern "C" void kernel_launch(void* const* d_in, const int* in_sizes, int n_in,
                              void* d_out, int out_size, void* d_ws, size_t ws_size,
                              hipStream_t stream) {
    const float* vw = (const float*)d_in[0];
    float* out = (float*)d_out;

    int*      rank_g = (int*)d_ws;                        // 3*4096 ints
    unsigned* word_g = (unsigned*)(rank_g + CH * N_PIX);  // 2*3*4096 uints

    ct_rank_build<<<48, 256, 0, stream>>>(vw, rank_g, word_g);
    ct_assemble<<<CH, 1024, 0, stream>>>(vw, rank_g, word_g, out);
}